// Round 14
// baseline (153.941 us; speedup 1.0000x reference)
//
#include <hip/hip_runtime.h>
#include <cstddef>
#include <cstdint>

// B=256, N=32, F=40, H=M=100, EF=4, OUT=128, 3 passes.
#define B_   256
#define N_   32
#define F_   40
#define H_   100
#define OUT_ 128
#define TB   1024         // 16 waves/block -> 4 waves/SIMD, 1 block/CU
#define XCS  168          // XcH/XcL row stride (shorts)
#define XMS  136          // Xy row stride (shorts)
#define ST2  40           // XcT row stride (shorts): [k][n], b128-aligned
#define NBLK 483          // AFhi blocks: 336 fused-G + 84 hh + 35 Wg + 28 We
#define NLO  63           // AFlo blocks (readout lo)

using bf16x8 = __attribute__((ext_vector_type(8))) short;   // 8 bf16 (4 VGPRs)
using f32x4  = __attribute__((ext_vector_type(4))) float;   // MFMA C/D

__device__ __forceinline__ float sigmoidf_(float x){ return 1.0f/(1.0f+__expf(-x)); }
__device__ __forceinline__ float tanhf_(float x){           // fast tanh via exp2-based expf
  float e = __expf(2.0f*x);
  return 1.0f - 2.0f/(e+1.0f);
}
__device__ __forceinline__ float bf2f(short s){ return __uint_as_float(((uint32_t)(uint16_t)s)<<16); }
__device__ __forceinline__ short f2bf(float x){             // round-to-nearest-even
  uint32_t u = __float_as_uint(x);
  return (short)((u + 0x7FFFu + ((u>>16)&1u))>>16);
}
__device__ __forceinline__ void bsplit(float x, short& hi, short& lo){
  hi = f2bf(x);
  lo = f2bf(x - bf2f(hi));
}

// ---------------------------------------------------------------------------
// Weight pre-pack v3: one thread per A-fragment SLOT (writes 0 for OOR -> no
// memset dispatch). Fused G blocks hold G_{g,t} = W_ih_g @ W_msg_t computed
// here in fp32 (100-MAC dot per slot; weights are L2-resident).
// Block table:
//   [0,336)   fused G: blk=((g*4+t)*28)+jmt*4+ks   A[j][h]=sum_m Wih_g[j,m]*Wt[m,h]
//   [336,420) hh     : 336+mat*28+jmt*4+ks         A[j][k]=W_hh[mat*100+j, k]
//   [420,455) Wg^T   : 420+jmt*5+ks (K=140, hi+lo) A[j][k]=Wg[k, j]
//   [455,483) We^T   : 455+jmt*4+ks (hi+lo)        A[j][k]=We[k, j]
// Lane map: A[m=lane&15][k=(lane>>4)*8+jj].
// ---------------------------------------------------------------------------
__global__ void prep_frags3(const float* __restrict__ Wmsg,
                            const float* __restrict__ Wih,
                            const float* __restrict__ Whh,
                            const float* __restrict__ Wg,
                            const float* __restrict__ We,
                            short* __restrict__ AFhi,
                            short* __restrict__ AFlo){
  int slot = blockIdx.x*blockDim.x + threadIdx.x;
  if (slot >= NBLK*512) return;
  int blk = slot>>9, r = slot&511, lane = r>>3, jj = r&7;
  int m = lane&15, q = lane>>4, kl = q*8+jj;
  if (blk < 336){
    int sub = blk/28, rem = blk%28;
    int g = sub>>2, t = sub&3, jmt = rem>>2, ks = rem&3;
    int jo = jmt*16+m, h = ks*32+kl;
    float v = 0.0f;
    if (jo<100 && h<100){
      const float* wr = Wih + (g*100+jo)*100;      // contiguous over m2
      const float* wc = Wmsg + h*4 + t;            // stride 400B over m2
#pragma unroll 4
      for (int m2=0;m2<100;++m2) v += wr[m2]*wc[m2*400];
    }
    AFhi[slot] = f2bf(v);
  } else if (blk < 420){
    int bb = blk-336, mat = bb/28, rem = bb%28, jmt = rem>>2, ks = rem&3;
    int jo = jmt*16+m, k = ks*32+kl;
    float v = (jo<100 && k<100) ? Whh[(mat*100+jo)*100+k] : 0.0f;
    AFhi[slot] = f2bf(v);
  } else if (blk < 455){
    int bb = blk-420, jmt = bb/5, ks = bb%5;
    int jo = jmt*16+m, k = ks*32+kl;
    float v = (jo<100 && k<140) ? Wg[k*100+jo] : 0.0f;
    short hi,lo; bsplit(v,hi,lo);
    AFhi[slot] = hi;
    AFlo[(size_t)(blk-420)*512 + lane*8 + jj] = lo;
  } else {
    int bb = blk-455, jmt = bb>>2, ks = bb&3;
    int jo = jmt*16+m, k = ks*32+kl;
    float v = (jo<100 && k<100) ? We[k*100+jo] : 0.0f;
    short hi,lo; bsplit(v,hi,lo);
    AFhi[slot] = hi;
    AFlo[(size_t)(blk-420)*512 + lane*8 + jj] = lo;
  }
}

// B-operand fragment from LDS [n][k] bf16: lane holds B[k=(lane>>4)*8+j][n=lane&15]
__device__ __forceinline__ bf16x8 ldB(const short* X, int stride, int nt, int ks, int lane){
  int n = nt*16 + (lane&15);
  return *(const bf16x8*)&X[n*stride + ks*32 + (lane>>4)*8];
}
__device__ __forceinline__ bf16x8 ldA(const short* __restrict__ AF, int blk, int lane){
  return *(const bf16x8*)(AF + (size_t)blk*512 + lane*8);
}

// ---------------------------------------------------------------------------
// Fused MPNN, one block per batch, 1024 threads, 14 tile-tasks (jmt<7 x nt<2).
// Per pass (2 barriers):
//   [Y-agg: Y_t = A_t h via 4 MFMA from pass-invariant adjacency frags] bar
//   [gi: 48 mm1 from fused G; hh: 12 mm1; elementwise -> XcH/XcT next buf] bar
// Xc double-buffered (hi + transposed) so elementwise fuses into GEMM region.
// #pragma unroll 1 + depth-2 prefetch everywhere (spill guard, R6-R12).
// ---------------------------------------------------------------------------
__global__ __launch_bounds__(TB, 4) void mpnn_mfma(
    const float* __restrict__ nodes, const float* __restrict__ edges,
    const short* __restrict__ AFhi, const short* __restrict__ AFlo,
    const float* __restrict__ b_ih, const float* __restrict__ b_hh,
    const float* __restrict__ bg, const float* __restrict__ be,
    const float* __restrict__ Wo, const float* __restrict__ bo,
    float* __restrict__ out){
  const int b = blockIdx.x;
  const int tid = threadIdx.x;
  const int lane = tid & 63;
  const int w = tid >> 6;

  __shared__ short XcH[2][32*XCS];   // cat: h | nodes(100..139) | 0  (dbuf hi)
  __shared__ short XcL[32*XCS];      // h state lo (rows 0..99)
  __shared__ short XcT[2][112*ST2];  // transposed h [k][n] (dbuf, Y-agg B)
  __shared__ short XyH[4*32*XMS];    // per-type Y_t (bf16)
  __shared__ short Aw[4*32*32];      // adjacency A-frag source [t][n][g]
  __shared__ float sh_ge[H_];
  __shared__ float sh_part[4][OUT_];
  __shared__ float sh_rowsum[N_];

  // ---- zero LDS (never-written slots must be 0, not garbage-NaN) -----------
  for (int i=tid;i<32*XCS;i+=TB){ XcH[0][i]=0; XcH[1][i]=0; XcL[i]=0; }
  for (int i=tid;i<2*112*ST2;i+=TB){ ((short*)XcT)[i]=0; }
  for (int i=tid;i<4*32*XMS;i+=TB){ XyH[i]=0; }
  for (int i=tid;i<4*32*32;i+=TB){ Aw[i]=0; }
  if (tid < H_) sh_ge[tid]=0.0f;
  if (tid < N_) sh_rowsum[tid]=0.0f;
  __syncthreads();

  // ---- edge staging: adjacency frag source + row sums (tid == (n,g)) ------
  {
    int n = tid>>5, g = tid&31;
    const float4 ev = *(const float4*)(edges + (((size_t)b*N_+n)*N_+g)*4);
    float adj = ev.x+ev.y+ev.z+ev.w;
    if (adj != 0.0f){
      atomicAdd(&sh_rowsum[n], adj);
      float ef[4] = {ev.x,ev.y,ev.z,ev.w};
      for (int f=0; f<4; ++f)
        if (ef[f] != 0.0f) Aw[f*1024 + n*32 + g] = f2bf(ef[f]);
    }
  }
  // ---- node staging (grid-stride: 1280 > TB!) ------------------------------
  for (int p=tid; p<N_*F_; p+=TB){
    int n = p/F_, f = p%F_;
    float x = nodes[((size_t)b*N_+n)*F_ + f];
    short hi,lo; bsplit(x,hi,lo);
    XcH[0][n*XCS+f]=hi;       XcL[n*XCS+f]=lo;       // h init (buf0)
    XcH[0][n*XCS+100+f]=hi;   XcH[1][n*XCS+100+f]=hi;// static cat rows both bufs
    XcT[0][f*ST2+n]=hi;                               // transposed h init
  }
  __syncthreads();

  const int jmt = w>>1, nt = w&1;
  const bool task = (w < 14);
  int cur = 0;

  for (int pass=0; pass<3; ++pass){
    const int nxt = cur^1;
    // ---- Y-agg: Y_t[n][kf] = sum_g A_t[n][g] h[g][kf], 4 MFMA --------------
    if (task){
      bf16x8 bfr = *(const bf16x8*)&XcT[cur][(jmt*16+(lane&15))*ST2 + (lane>>4)*8];
      int kf = jmt*16 + (lane&15);
#pragma unroll
      for (int t=0;t<4;++t){
        bf16x8 af = *(const bf16x8*)&Aw[t*1024 + (nt*16+(lane&15))*32 + (lane>>4)*8];
        f32x4 D = (f32x4)0.0f;
        D = __builtin_amdgcn_mfma_f32_16x16x32_bf16(af, bfr, D, 0,0,0);
        if (kf < 100){
#pragma unroll
          for (int r=0;r<4;++r)
            XyH[t*32*XMS + (nt*16+(lane>>4)*4+r)*XMS + kf] = f2bf(D[r]);
        }
      }
    }
    __syncthreads();
    // ---- gi (48 mm1, fused G) + hh (12 mm1) + elementwise ------------------
    if (task){
      f32x4 Cg0=(f32x4)0.0f, Cg1=(f32x4)0.0f, Cg2=(f32x4)0.0f;
      {
        bf16x8 ah = ldA(AFhi, jmt*4, lane);
        bf16x8 bh = ldB(XyH, XMS, nt, 0, lane);
#pragma unroll 1
        for (int i=0;i<48;++i){
          int ip = (i<47)? i+1 : 47;
          int gp = ip>>4, tp = (ip>>2)&3, ksp = ip&3;
          bf16x8 an  = ldA(AFhi, (gp*4+tp)*28 + jmt*4 + ksp, lane);
          bf16x8 bhn = ldB(XyH + tp*32*XMS, XMS, nt, ksp, lane);
          int g = i>>4;
          if (g==0)      Cg0 = __builtin_amdgcn_mfma_f32_16x16x32_bf16(ah, bh, Cg0, 0,0,0);
          else if (g==1) Cg1 = __builtin_amdgcn_mfma_f32_16x16x32_bf16(ah, bh, Cg1, 0,0,0);
          else           Cg2 = __builtin_amdgcn_mfma_f32_16x16x32_bf16(ah, bh, Cg2, 0,0,0);
          ah = an; bh = bhn;
        }
      }
      f32x4 Ch0=(f32x4)0.0f, Ch1=(f32x4)0.0f, Ch2=(f32x4)0.0f;
      {
        bf16x8 ah = ldA(AFhi, 336 + jmt*4, lane);
        bf16x8 bh = ldB(XcH[cur], XCS, nt, 0, lane);
#pragma unroll 1
        for (int i=0;i<12;++i){
          int ip = (i<11)? i+1 : 11;
          int mp = ip>>2, ksp = ip&3;
          bf16x8 an  = ldA(AFhi, 336 + mp*28 + jmt*4 + ksp, lane);
          bf16x8 bhn = ldB(XcH[cur], XCS, nt, ksp, lane);
          int g = i>>2;
          if (g==0)      Ch0 = __builtin_amdgcn_mfma_f32_16x16x32_bf16(ah, bh, Ch0, 0,0,0);
          else if (g==1) Ch1 = __builtin_amdgcn_mfma_f32_16x16x32_bf16(ah, bh, Ch1, 0,0,0);
          else           Ch2 = __builtin_amdgcn_mfma_f32_16x16x32_bf16(ah, bh, Ch2, 0,0,0);
          ah = an; bh = bhn;
        }
      }
      int n = nt*16+(lane&15);
      bool msk = (sh_rowsum[n] != 0.0f);
#pragma unroll
      for (int r=0;r<4;++r){
        int row = jmt*16 + (lane>>4)*4 + r;
        if (row<100){
          float ho = bf2f(XcH[cur][n*XCS+row]) + bf2f(XcL[n*XCS+row]);
          float rr = sigmoidf_(Cg0[r]+Ch0[r] + b_ih[row]     + b_hh[row]);
          float zz = sigmoidf_(Cg1[r]+Ch1[r] + b_ih[100+row] + b_hh[100+row]);
          float nn = tanhf_(Cg2[r] + b_ih[200+row] + rr*(Ch2[r] + b_hh[200+row]));
          float hnew = (1.0f-zz)*nn + zz*ho;
          if (!msk) hnew = ho;
          short hi,lo; bsplit(hnew,hi,lo);
          XcH[nxt][n*XCS+row]=hi; XcL[n*XCS+row]=lo; XcT[nxt][row*ST2+n]=hi;
        }
      }
    }
    __syncthreads();
    cur ^= 1;
  }

  // ---- readout: gate/emb GEMMs (A hi+lo, prefetched), masked sum -----------
  f32x4 Cg=(f32x4)0.0f, Ce=(f32x4)0.0f;
  if (task){
    bf16x8 ah = ldA(AFhi, 420+jmt*5, lane);
    bf16x8 al = ldA(AFlo, jmt*5, lane);
    bf16x8 bh = ldB(XcH[cur], XCS, nt, 0, lane);
#pragma unroll 1
    for (int i=0;i<9;++i){
      int ip = (i<8)? i+1 : 8;
      int blkp = (ip<5)? 420+jmt*5+ip : 455+jmt*4+(ip-5);
      int ksp  = (ip<5)? ip : ip-5;
      bf16x8 an  = ldA(AFhi, blkp, lane);
      bf16x8 aln = ldA(AFlo, blkp-420, lane);
      bf16x8 bhn = ldB(XcH[cur], XCS, nt, ksp, lane);
      if (i<5){
        Cg = __builtin_amdgcn_mfma_f32_16x16x32_bf16(ah, bh, Cg, 0,0,0);
        Cg = __builtin_amdgcn_mfma_f32_16x16x32_bf16(al, bh, Cg, 0,0,0);
      } else {
        Ce = __builtin_amdgcn_mfma_f32_16x16x32_bf16(ah, bh, Ce, 0,0,0);
        Ce = __builtin_amdgcn_mfma_f32_16x16x32_bf16(al, bh, Ce, 0,0,0);
      }
      ah = an; al = aln; bh = bhn;
    }
    int n = nt*16+(lane&15);
    bool msk = (sh_rowsum[n] != 0.0f);
#pragma unroll
    for (int r=0;r<4;++r){
      int row = jmt*16 + (lane>>4)*4 + r;
      float v = 0.0f;
      if (row<100){
        float gate = sigmoidf_(Cg[r] + bg[row]);
        float emb  = gate*(Ce[r] + be[row]);
        v = msk ? emb : 0.0f;
      }
      v += __shfl_xor(v, 1);
      v += __shfl_xor(v, 2);
      v += __shfl_xor(v, 4);
      v += __shfl_xor(v, 8);
      if (row<100 && (lane&15)==0) atomicAdd(&sh_ge[row], v);
    }
  }
  __syncthreads();
  // ---- out = graph_emb @ Wo + bo : 512 threads, 4 k-chunks of 25 -----------
  if (tid < 512){
    int o = tid & 127, q = tid >> 7;
    float s = 0.0f;
    int k0 = 25*q;
#pragma unroll 5
    for (int k=k0; k<k0+25; ++k) s += sh_ge[k]*Wo[k*OUT_+o];
    sh_part[q][o] = s;
  }
  __syncthreads();
  if (tid < OUT_){
    out[(size_t)b*OUT_ + tid] = bo[tid] + sh_part[0][tid] + sh_part[1][tid]
                              + sh_part[2][tid] + sh_part[3][tid];
  }
}

extern "C" void kernel_launch(void* const* d_in, const int* in_sizes, int n_in,
                              void* d_out, int out_size, void* d_ws, size_t ws_size,
                              hipStream_t stream){
  const float* nodes = (const float*)d_in[0];
  const float* edges = (const float*)d_in[1];
  const float* W_msg = (const float*)d_in[2];
  const float* W_ih  = (const float*)d_in[3];
  const float* W_hh  = (const float*)d_in[4];
  const float* b_ih  = (const float*)d_in[5];
  const float* b_hh  = (const float*)d_in[6];
  const float* Wg    = (const float*)d_in[7];
  const float* bg    = (const float*)d_in[8];
  const float* We    = (const float*)d_in[9];
  const float* be    = (const float*)d_in[10];
  const float* Wo    = (const float*)d_in[11];
  const float* bo    = (const float*)d_in[12];

  short* AFhi = (short*)d_ws;                        // 483*512 shorts = 483 KB
  short* AFlo = AFhi + (size_t)NBLK*512;             //  63*512 shorts =  63 KB

  prep_frags3<<<(NBLK*512 + 255)/256, 256, 0, stream>>>(W_msg, W_ih, W_hh, Wg, We,
                                                        AFhi, AFlo);
  mpnn_mfma<<<B_, TB, 0, stream>>>(nodes, edges, AFhi, AFlo, b_ih, b_hh, bg, be,
                                   Wo, bo, (float*)d_out);
}

// Round 15
// 117.363 us; speedup vs baseline: 1.3117x; 1.3117x over previous
//
#include <hip/hip_runtime.h>
#include <cstddef>
#include <cstdint>

// B=256, N=32, F=40, H=M=100, EF=4, OUT=128, 3 passes.
#define B_   256
#define N_   32
#define F_   40
#define H_   100
#define OUT_ 128
#define CAP_ 8
#define TB   1024         // 16 waves/block -> 4 waves/SIMD, 1 block/CU
#define XCS  168          // XcH/XcL row stride (shorts), 16B-multiple
#define XMS  136          // Xm / Xy row stride (shorts), 16B-multiple
#define NBLK 343          // AFhi blocks: 112 msg + 168 GRU + 35 Wg + 28 We
#define NLO  63           // AFlo blocks (readout lo)

using bf16x8 = __attribute__((ext_vector_type(8))) short;   // 8 bf16 (4 VGPRs)
using f32x4  = __attribute__((ext_vector_type(4))) float;   // MFMA C/D

#define MFMA(a,b,c) __builtin_amdgcn_mfma_f32_16x16x32_bf16((a),(b),(c),0,0,0)

__device__ __forceinline__ float sigmoidf_(float x){ return 1.0f/(1.0f+__expf(-x)); }
__device__ __forceinline__ float tanhf_(float x){           // fast tanh via __expf
  float e = __expf(2.0f*x);
  return 1.0f - 2.0f/(e+1.0f);
}
__device__ __forceinline__ float bf2f(short s){ return __uint_as_float(((uint32_t)(uint16_t)s)<<16); }
__device__ __forceinline__ short f2bf(float x){             // round-to-nearest-even
  uint32_t u = __float_as_uint(x);
  return (short)((u + 0x7FFFu + ((u>>16)&1u))>>16);
}
__device__ __forceinline__ void bsplit(float x, short& hi, short& lo){
  hi = f2bf(x);
  lo = f2bf(x - bf2f(hi));
}

// ---------------------------------------------------------------------------
// Weight pre-pack v4: SLOT-indexed (one thread per fragment slot; writes 0
// for out-of-range rows/cols -> no memset dispatch needed).
// Block table (R13 layout):
//   [0,112)   W_msg : t*28 + jmt*4 + ks        A[m][h]=W_msg[m, h, t]
//   [112,280) GRU   : 112+mat*28+jmt*4+ks      mat: ihr,ihz,ihn,hhr,hhz,hhn
//   [280,315) Wg^T  : 280+jmt*5+ks (K=140)     A[j][k]=Wg[k, j]  (hi+lo)
//   [315,343) We^T  : 315+jmt*4+ks             A[j][k]=We[k, j]  (hi+lo)
// Lane map: A[m=lane&15][k=(lane>>4)*8+jj].
// ---------------------------------------------------------------------------
__global__ void prep_frags4(const float* __restrict__ Wmsg,
                            const float* __restrict__ Wih,
                            const float* __restrict__ Whh,
                            const float* __restrict__ Wg,
                            const float* __restrict__ We,
                            short* __restrict__ AFhi,
                            short* __restrict__ AFlo){
  int slot = blockIdx.x*blockDim.x + threadIdx.x;
  if (slot >= NBLK*512) return;
  int blk = slot>>9, r = slot&511, lane = r>>3, jj = r&7;
  int m = lane&15, q = lane>>4, kl = q*8+jj;
  float v = 0.0f;
  if (blk < 112){
    int t = blk/28, rem = blk%28, jmt = rem>>2, ks = rem&3;
    int mg = jmt*16+m, h = ks*32+kl;
    if (mg<100 && h<100) v = Wmsg[(mg*100+h)*4 + t];
    AFhi[slot] = f2bf(v);
  } else if (blk < 280){
    int bb = blk-112, mat = bb/28, rem = bb%28, jmt = rem>>2, ks = rem&3;
    int mg = jmt*16+m, k = ks*32+kl;
    if (mg<100 && k<100)
      v = (mat<3) ? Wih[(mat*100+mg)*100+k] : Whh[((mat-3)*100+mg)*100+k];
    AFhi[slot] = f2bf(v);
  } else if (blk < 315){
    int bb = blk-280, jmt = bb/5, ks = bb%5;
    int mg = jmt*16+m, k = ks*32+kl;
    if (mg<100 && k<140) v = Wg[k*100+mg];
    short hi,lo; bsplit(v,hi,lo);
    AFhi[slot] = hi;
    AFlo[(size_t)(blk-280)*512 + r] = lo;
  } else {
    int bb = blk-315, jmt = bb>>2, ks = bb&3;
    int mg = jmt*16+m, k = ks*32+kl;
    if (mg<100 && k<100) v = We[k*100+mg];
    short hi,lo; bsplit(v,hi,lo);
    AFhi[slot] = hi;
    AFlo[(size_t)(blk-280)*512 + r] = lo;
  }
}

// ---------------------------------------------------------------------------
// Fused MPNN (R13 dataflow, VALU-stripped): one block per batch, 1024 threads,
// 14 tile-tasks (jmt<7 x nt<2). 3 barriers/pass:
//   [Y-build] bar [msg(16 mm1)+hh(12 mm1)+Xm write] bar [ih(12)+elementwise] bar
// GEMM loops: ks unrolled x4 with immediate-offset loads (no per-iter address
// VALU); B-fragments loaded ONCE per region and shared across the 3 gates.
// Outer loops stay #pragma unroll 1 (spill guard, R6-R9).
// ---------------------------------------------------------------------------
__global__ __launch_bounds__(TB, 4) void mpnn_mfma(
    const float* __restrict__ nodes, const float* __restrict__ edges,
    const short* __restrict__ AFhi, const short* __restrict__ AFlo,
    const float* __restrict__ b_ih, const float* __restrict__ b_hh,
    const float* __restrict__ bg, const float* __restrict__ be,
    const float* __restrict__ Wo, const float* __restrict__ bo,
    float* __restrict__ out){
  const int b = blockIdx.x;
  const int tid = threadIdx.x;
  const int lane = tid & 63;
  const int w = tid >> 6;

  __shared__ short XcH[32*XCS], XcL[32*XCS];      // cat: h | nodes(100..139) | 0
  __shared__ short XmH[32*XMS];                   // messages (bf16)
  __shared__ short XyH[4][32*XMS];                // per-type aggregated Y_t (bf16)
  __shared__ float sh_ge[H_];
  __shared__ float sh_part[4][OUT_];              // Wo-tail partials
  __shared__ float sh_rowsum[N_];
  __shared__ int   sh_cnt[N_];
  __shared__ int   sh_gt[N_][CAP_];               // packed (g<<2)|t
  __shared__ float sh_w[N_][CAP_];

  // ---- zero LDS (Xc rows>=140 and Xm rows>=100 must stay 0) ----------------
  for (int i=tid;i<(32*XCS)/2;i+=TB){ ((int*)XcH)[i]=0; ((int*)XcL)[i]=0; }
  for (int i=tid;i<(32*XMS)/2;i+=TB){ ((int*)XmH)[i]=0; }
  if (tid < H_) sh_ge[tid]=0.0f;
  if (tid < N_){ sh_cnt[tid]=0; sh_rowsum[tid]=0.0f; }
  __syncthreads();

  // ---- per-node neighbor lists + node staging ------------------------------
  {
    int n = tid>>5, g = tid&31;                 // TB == N*N
    const float4 ev = *(const float4*)(edges + (((size_t)b*N_+n)*N_+g)*4);
    float adj = ev.x+ev.y+ev.z+ev.w;
    if (adj != 0.0f){
      atomicAdd(&sh_rowsum[n], adj);
      float ef[4] = {ev.x,ev.y,ev.z,ev.w};
      for (int f=0; f<4; ++f)
        if (ef[f] != 0.0f){
          int s = atomicAdd(&sh_cnt[n],1);
          if (s<CAP_){ sh_gt[n][s]=(g<<2)|f; sh_w[n][s]=ef[f]; }
        }
    }
  }
  for (int p=tid; p<N_*F_; p+=TB){              // grid-stride: 1280 > TB
    int n = p/F_, f = p%F_;
    float x = nodes[((size_t)b*N_+n)*F_ + f];
    short hi,lo; bsplit(x,hi,lo);
    XcH[n*XCS+f]=hi;      XcL[n*XCS+f]=lo;      // h init rows 0..39
    XcH[n*XCS+100+f]=hi;                        // cat-tail rows 100..139
  }
  __syncthreads();

  const int jmt = w>>1, nt = w&1;               // task (w<14)
  const bool task = (w < 14);
  const int nrow = nt*16 + (lane&15);           // this lane's B-row (node)
  const int boff = (lane>>4)*8;                 // this lane's k-offset in frag

  for (int pass=0; pass<3; ++pass){
    // ---- build ALL Y_t in one sweep (bf16 in/out, distributed) -------------
    for (int it=0; it<2; ++it){
      int idx = tid + it*TB;                   // 0..2047
      int n = idx >> 6;                        // wave-uniform
      int kp = idx & 63;                       // int index: k = 2kp, 2kp+1
      int cnt = sh_cnt[n] < CAP_ ? sh_cnt[n] : CAP_;
      float s0[4]={0,0,0,0}, s1[4]={0,0,0,0};
      for (int e=0;e<cnt;++e){
        int gt = sh_gt[n][e];                  // wave-uniform -> scalar branch
        int g = gt>>2; float wv = sh_w[n][e];
        int hh = ((const int*)(XcH + g*XCS))[kp];
        float h0 = bf2f((short)(hh&0xffff));
        float h1 = bf2f((short)(hh>>16));
        int t = gt&3;
        if (t==0)      { s0[0]+=wv*h0; s1[0]+=wv*h1; }
        else if (t==1) { s0[1]+=wv*h0; s1[1]+=wv*h1; }
        else if (t==2) { s0[2]+=wv*h0; s1[2]+=wv*h1; }
        else           { s0[3]+=wv*h0; s1[3]+=wv*h1; }
      }
#pragma unroll
      for (int t=0;t<4;++t){
        ((int*)(XyH[t] + n*XMS))[kp] =
          (int)((uint16_t)f2bf(s0[t]) | ((uint32_t)(uint16_t)f2bf(s1[t])<<16));
      }
    }
    __syncthreads();
    // ---- region 1: msg (4 t-groups of 4 mm1) + hh (B shared across gates) --
    f32x4 Ch0=(f32x4)0.0f, Ch1=(f32x4)0.0f, Ch2=(f32x4)0.0f;
    if (task){
      f32x4 Cm=(f32x4)0.0f;
#pragma unroll 1
      for (int t=0;t<4;++t){
        const short* pa = AFhi + ((size_t)(t*28 + jmt*4))*512 + lane*8;
        const short* pb = XyH[t] + nrow*XMS + boff;
        bf16x8 a0 = *(const bf16x8*)(pa);
        bf16x8 a1 = *(const bf16x8*)(pa+512);
        bf16x8 a2 = *(const bf16x8*)(pa+1024);
        bf16x8 a3 = *(const bf16x8*)(pa+1536);
        bf16x8 b0 = *(const bf16x8*)(pb);
        bf16x8 b1 = *(const bf16x8*)(pb+32);
        bf16x8 b2 = *(const bf16x8*)(pb+64);
        bf16x8 b3 = *(const bf16x8*)(pb+96);
        Cm = MFMA(a0,b0,Cm); Cm = MFMA(a1,b1,Cm);
        Cm = MFMA(a2,b2,Cm); Cm = MFMA(a3,b3,Cm);
      }
      {  // hh gates: load XcH B-frags ONCE, reuse for 3 gates
        const short* pb = XcH + nrow*XCS + boff;
        bf16x8 b0 = *(const bf16x8*)(pb);
        bf16x8 b1 = *(const bf16x8*)(pb+32);
        bf16x8 b2 = *(const bf16x8*)(pb+64);
        bf16x8 b3 = *(const bf16x8*)(pb+96);
        const short* pa = AFhi + ((size_t)(112 + 3*28 + jmt*4))*512 + lane*8;
        {
          bf16x8 a0=*(const bf16x8*)(pa),      a1=*(const bf16x8*)(pa+512);
          bf16x8 a2=*(const bf16x8*)(pa+1024), a3=*(const bf16x8*)(pa+1536);
          Ch0 = MFMA(a0,b0,Ch0); Ch0 = MFMA(a1,b1,Ch0);
          Ch0 = MFMA(a2,b2,Ch0); Ch0 = MFMA(a3,b3,Ch0);
        }
        pa += 28*512;
        {
          bf16x8 a0=*(const bf16x8*)(pa),      a1=*(const bf16x8*)(pa+512);
          bf16x8 a2=*(const bf16x8*)(pa+1024), a3=*(const bf16x8*)(pa+1536);
          Ch1 = MFMA(a0,b0,Ch1); Ch1 = MFMA(a1,b1,Ch1);
          Ch1 = MFMA(a2,b2,Ch1); Ch1 = MFMA(a3,b3,Ch1);
        }
        pa += 28*512;
        {
          bf16x8 a0=*(const bf16x8*)(pa),      a1=*(const bf16x8*)(pa+512);
          bf16x8 a2=*(const bf16x8*)(pa+1024), a3=*(const bf16x8*)(pa+1536);
          Ch2 = MFMA(a0,b0,Ch2); Ch2 = MFMA(a1,b1,Ch2);
          Ch2 = MFMA(a2,b2,Ch2); Ch2 = MFMA(a3,b3,Ch2);
        }
      }
      for (int r=0;r<4;++r){                   // Xm write (disjoint from Xy/Xc)
        int row = jmt*16 + (lane>>4)*4 + r;
        if (row<100) XmH[nrow*XMS+row] = f2bf(Cm[r]);
      }
    }
    __syncthreads();
    // ---- region 2: ih gates (B=Xm shared) + GRU elementwise ----------------
    if (task){
      f32x4 Ci0=(f32x4)0.0f, Ci1=(f32x4)0.0f, Ci2=(f32x4)0.0f;
      {
        const short* pb = XmH + nrow*XMS + boff;
        bf16x8 b0 = *(const bf16x8*)(pb);
        bf16x8 b1 = *(const bf16x8*)(pb+32);
        bf16x8 b2 = *(const bf16x8*)(pb+64);
        bf16x8 b3 = *(const bf16x8*)(pb+96);
        const short* pa = AFhi + ((size_t)(112 + jmt*4))*512 + lane*8;
        {
          bf16x8 a0=*(const bf16x8*)(pa),      a1=*(const bf16x8*)(pa+512);
          bf16x8 a2=*(const bf16x8*)(pa+1024), a3=*(const bf16x8*)(pa+1536);
          Ci0 = MFMA(a0,b0,Ci0); Ci0 = MFMA(a1,b1,Ci0);
          Ci0 = MFMA(a2,b2,Ci0); Ci0 = MFMA(a3,b3,Ci0);
        }
        pa += 28*512;
        {
          bf16x8 a0=*(const bf16x8*)(pa),      a1=*(const bf16x8*)(pa+512);
          bf16x8 a2=*(const bf16x8*)(pa+1024), a3=*(const bf16x8*)(pa+1536);
          Ci1 = MFMA(a0,b0,Ci1); Ci1 = MFMA(a1,b1,Ci1);
          Ci1 = MFMA(a2,b2,Ci1); Ci1 = MFMA(a3,b3,Ci1);
        }
        pa += 28*512;
        {
          bf16x8 a0=*(const bf16x8*)(pa),      a1=*(const bf16x8*)(pa+512);
          bf16x8 a2=*(const bf16x8*)(pa+1024), a3=*(const bf16x8*)(pa+1536);
          Ci2 = MFMA(a0,b0,Ci2); Ci2 = MFMA(a1,b1,Ci2);
          Ci2 = MFMA(a2,b2,Ci2); Ci2 = MFMA(a3,b3,Ci2);
        }
      }
      bool msk = (sh_rowsum[nrow] != 0.0f);
#pragma unroll
      for (int r=0;r<4;++r){
        int row = jmt*16 + (lane>>4)*4 + r;
        if (row<100){
          float ho = bf2f(XcH[nrow*XCS+row]) + bf2f(XcL[nrow*XCS+row]);
          float rr = sigmoidf_(Ci0[r]+Ch0[r] + b_ih[row]     + b_hh[row]);
          float zz = sigmoidf_(Ci1[r]+Ch1[r] + b_ih[100+row] + b_hh[100+row]);
          float nn = tanhf_(Ci2[r] + b_ih[200+row] + rr*(Ch2[r] + b_hh[200+row]));
          float hnew = (1.0f-zz)*nn + zz*ho;
          if (!msk) hnew = ho;
          short hi,lo; bsplit(hnew,hi,lo);
          XcH[nrow*XCS+row]=hi; XcL[nrow*XCS+row]=lo;
        }
      }
    }
    __syncthreads();
  }

  // ---- readout: gate/emb GEMMs (A hi+lo, B=XcH shared), masked sum ---------
  f32x4 Cg=(f32x4)0.0f, Ce=(f32x4)0.0f;
  if (task){
    const short* pb = XcH + nrow*XCS + boff;
    bf16x8 b0 = *(const bf16x8*)(pb);
    bf16x8 b1 = *(const bf16x8*)(pb+32);
    bf16x8 b2 = *(const bf16x8*)(pb+64);
    bf16x8 b3 = *(const bf16x8*)(pb+96);
    bf16x8 b4 = *(const bf16x8*)(pb+128);
    {  // Wg: blocks 280+jmt*5 .. +4 (hi) and same-idx lo
      const short* ph = AFhi + ((size_t)(280 + jmt*5))*512 + lane*8;
      const short* pl = AFlo + ((size_t)(jmt*5))*512 + lane*8;
      Cg = MFMA(*(const bf16x8*)(ph),      b0, Cg);
      Cg = MFMA(*(const bf16x8*)(pl),      b0, Cg);
      Cg = MFMA(*(const bf16x8*)(ph+512),  b1, Cg);
      Cg = MFMA(*(const bf16x8*)(pl+512),  b1, Cg);
      Cg = MFMA(*(const bf16x8*)(ph+1024), b2, Cg);
      Cg = MFMA(*(const bf16x8*)(pl+1024), b2, Cg);
      Cg = MFMA(*(const bf16x8*)(ph+1536), b3, Cg);
      Cg = MFMA(*(const bf16x8*)(pl+1536), b3, Cg);
      Cg = MFMA(*(const bf16x8*)(ph+2048), b4, Cg);
      Cg = MFMA(*(const bf16x8*)(pl+2048), b4, Cg);
    }
    {  // We: blocks 315+jmt*4 .. +3 (hi), lo at (blk-280)
      const short* ph = AFhi + ((size_t)(315 + jmt*4))*512 + lane*8;
      const short* pl = AFlo + ((size_t)(35 + jmt*4))*512 + lane*8;
      Ce = MFMA(*(const bf16x8*)(ph),      b0, Ce);
      Ce = MFMA(*(const bf16x8*)(pl),      b0, Ce);
      Ce = MFMA(*(const bf16x8*)(ph+512),  b1, Ce);
      Ce = MFMA(*(const bf16x8*)(pl+512),  b1, Ce);
      Ce = MFMA(*(const bf16x8*)(ph+1024), b2, Ce);
      Ce = MFMA(*(const bf16x8*)(pl+1024), b2, Ce);
      Ce = MFMA(*(const bf16x8*)(ph+1536), b3, Ce);
      Ce = MFMA(*(const bf16x8*)(pl+1536), b3, Ce);
    }
    bool msk = (sh_rowsum[nrow] != 0.0f);
#pragma unroll
    for (int r=0;r<4;++r){
      int row = jmt*16 + (lane>>4)*4 + r;
      float v = 0.0f;
      if (row<100){
        float gate = sigmoidf_(Cg[r] + bg[row]);
        float emb  = gate*(Ce[r] + be[row]);
        v = msk ? emb : 0.0f;
      }
      v += __shfl_xor(v, 1);                   // reduce across 16 cols
      v += __shfl_xor(v, 2);
      v += __shfl_xor(v, 4);
      v += __shfl_xor(v, 8);
      if (row<100 && (lane&15)==0) atomicAdd(&sh_ge[row], v);
    }
  }
  __syncthreads();
  // ---- out = graph_emb @ Wo + bo : 512 threads, 4 k-chunks of 25 -----------
  if (tid < 512){
    int o = tid & 127, q = tid >> 7;           // lanes consecutive in o -> coalesced
    float s = 0.0f;
    int k0 = 25*q;
#pragma unroll 5
    for (int k=k0; k<k0+25; ++k) s += sh_ge[k]*Wo[k*OUT_+o];
    sh_part[q][o] = s;
  }
  __syncthreads();
  if (tid < OUT_){
    out[(size_t)b*OUT_ + tid] = bo[tid] + sh_part[0][tid] + sh_part[1][tid]
                              + sh_part[2][tid] + sh_part[3][tid];
  }
}

extern "C" void kernel_launch(void* const* d_in, const int* in_sizes, int n_in,
                              void* d_out, int out_size, void* d_ws, size_t ws_size,
                              hipStream_t stream){
  const float* nodes = (const float*)d_in[0];
  const float* edges = (const float*)d_in[1];
  const float* W_msg = (const float*)d_in[2];
  const float* W_ih  = (const float*)d_in[3];
  const float* W_hh  = (const float*)d_in[4];
  const float* b_ih  = (const float*)d_in[5];
  const float* b_hh  = (const float*)d_in[6];
  const float* Wg    = (const float*)d_in[7];
  const float* bg    = (const float*)d_in[8];
  const float* We    = (const float*)d_in[9];
  const float* be    = (const float*)d_in[10];
  const float* Wo    = (const float*)d_in[11];
  const float* bo    = (const float*)d_in[12];

  short* AFhi = (short*)d_ws;                        // 343*512 shorts = 343 KB
  short* AFlo = AFhi + (size_t)NBLK*512;             //  63*512 shorts =  63 KB

  prep_frags4<<<(NBLK*512 + 255)/256, 256, 0, stream>>>(W_msg, W_ih, W_hh, Wg, We,
                                                        AFhi, AFlo);
  mpnn_mfma<<<B_, TB, 0, stream>>>(nodes, edges, AFhi, AFlo, b_ih, b_hh, bg, be,
                                   Wo, bo, (float*)d_out);
}

// Round 16
// 114.511 us; speedup vs baseline: 1.3443x; 1.0249x over previous
//
#include <hip/hip_runtime.h>
#include <cstddef>
#include <cstdint>

// B=256, N=32, F=40, H=M=100, EF=4, OUT=128, 3 passes.
#define B_   256
#define N_   32
#define F_   40
#define H_   100
#define OUT_ 128
#define TB   1024         // 16 waves/block -> 4 waves/SIMD, 1 block/CU
#define XCS  168          // XcH/XcL row stride (shorts), 16B-multiple
#define XMS  136          // Xm / Xy row stride (shorts), 16B-multiple
#define ST2  40           // XcT row stride (shorts): [k][g], 16B-multiple
#define NBLK 343          // AFhi blocks: 112 msg + 168 GRU + 35 Wg + 28 We
#define NLO  63           // AFlo blocks (readout lo)

using bf16x8 = __attribute__((ext_vector_type(8))) short;   // 8 bf16 (4 VGPRs)
using f32x4  = __attribute__((ext_vector_type(4))) float;   // MFMA C/D

#define MFMA(a,b,c) __builtin_amdgcn_mfma_f32_16x16x32_bf16((a),(b),(c),0,0,0)

__device__ __forceinline__ float sigmoidf_(float x){ return 1.0f/(1.0f+__expf(-x)); }
__device__ __forceinline__ float tanhf_(float x){           // fast tanh via __expf
  float e = __expf(2.0f*x);
  return 1.0f - 2.0f/(e+1.0f);
}
__device__ __forceinline__ float bf2f(short s){ return __uint_as_float(((uint32_t)(uint16_t)s)<<16); }
__device__ __forceinline__ short f2bf(float x){             // round-to-nearest-even
  uint32_t u = __float_as_uint(x);
  return (short)((u + 0x7FFFu + ((u>>16)&1u))>>16);
}
__device__ __forceinline__ void bsplit(float x, short& hi, short& lo){
  hi = f2bf(x);
  lo = f2bf(x - bf2f(hi));
}

// ---------------------------------------------------------------------------
// Weight pre-pack v4 (unchanged layout): SLOT-indexed, OOR slots get 0.
//   [0,112)   W_msg : t*28 + jmt*4 + ks        A[m][h]=W_msg[m, h, t]
//   [112,280) GRU   : 112+mat*28+jmt*4+ks      mat: ihr,ihz,ihn,hhr,hhz,hhn
//   [280,315) Wg^T  : 280+jmt*5+ks (K=140)     A[j][k]=Wg[k, j]  (hi+lo)
//   [315,343) We^T  : 315+jmt*4+ks             A[j][k]=We[k, j]  (hi+lo)
// ---------------------------------------------------------------------------
__global__ void prep_frags4(const float* __restrict__ Wmsg,
                            const float* __restrict__ Wih,
                            const float* __restrict__ Whh,
                            const float* __restrict__ Wg,
                            const float* __restrict__ We,
                            short* __restrict__ AFhi,
                            short* __restrict__ AFlo){
  int slot = blockIdx.x*blockDim.x + threadIdx.x;
  if (slot >= NBLK*512) return;
  int blk = slot>>9, r = slot&511, lane = r>>3, jj = r&7;
  int m = lane&15, q = lane>>4, kl = q*8+jj;
  float v = 0.0f;
  if (blk < 112){
    int t = blk/28, rem = blk%28, jmt = rem>>2, ks = rem&3;
    int mg = jmt*16+m, h = ks*32+kl;
    if (mg<100 && h<100) v = Wmsg[(mg*100+h)*4 + t];
    AFhi[slot] = f2bf(v);
  } else if (blk < 280){
    int bb = blk-112, mat = bb/28, rem = bb%28, jmt = rem>>2, ks = rem&3;
    int mg = jmt*16+m, k = ks*32+kl;
    if (mg<100 && k<100)
      v = (mat<3) ? Wih[(mat*100+mg)*100+k] : Whh[((mat-3)*100+mg)*100+k];
    AFhi[slot] = f2bf(v);
  } else if (blk < 315){
    int bb = blk-280, jmt = bb/5, ks = bb%5;
    int mg = jmt*16+m, k = ks*32+kl;
    if (mg<100 && k<140) v = Wg[k*100+mg];
    short hi,lo; bsplit(v,hi,lo);
    AFhi[slot] = hi;
    AFlo[(size_t)(blk-280)*512 + r] = lo;
  } else {
    int bb = blk-315, jmt = bb>>2, ks = bb&3;
    int mg = jmt*16+m, k = ks*32+kl;
    if (mg<100 && k<100) v = We[k*100+mg];
    short hi,lo; bsplit(v,hi,lo);
    AFhi[slot] = hi;
    AFlo[(size_t)(blk-280)*512 + r] = lo;
  }
}

// ---------------------------------------------------------------------------
// Fused MPNN. 14 tile-tasks (jmt<7 x nt<2), one per wave. 3 tight barriers/pass:
//  [Y-agg: Y_t = h^T · a_t^T, 4 MFMA/wave, b64 C-writes] bar
//  [msg(16 mm1) + hh(12 mm1, B shared) + Xm write] bar
//  [ih(12 mm1, B shared) + GRU elementwise -> XcH/XcL/XcT] bar
// Y-agg orientation: A = XcT[k][g] (transposed h, g contig), B = Aw[t][n][g]
// (pass-invariant adjacency, g contig). C-layout rows = contiguous k => the
// 4 accs pack into ONE short4 LDS write (R14's row-scatter was 16 b16s).
// GEMM loops: immediate-offset unroll-4, outer #pragma unroll 1 (spill guard).
// ---------------------------------------------------------------------------
__global__ __launch_bounds__(TB, 4) void mpnn_mfma(
    const float* __restrict__ nodes, const float* __restrict__ edges,
    const short* __restrict__ AFhi, const short* __restrict__ AFlo,
    const float* __restrict__ b_ih, const float* __restrict__ b_hh,
    const float* __restrict__ bg, const float* __restrict__ be,
    const float* __restrict__ Wo, const float* __restrict__ bo,
    float* __restrict__ out){
  const int b = blockIdx.x;
  const int tid = threadIdx.x;
  const int lane = tid & 63;
  const int w = tid >> 6;

  __shared__ short XcH[32*XCS], XcL[32*XCS];      // cat: h | nodes(100..139) | 0
  __shared__ short XcT[112*ST2];                  // transposed h [k][g]
  __shared__ short XmH[32*XMS];                   // messages (bf16)
  __shared__ short XyH[4][32*XMS];                // per-type Y_t (bf16) [n][k]
  __shared__ short Aw[4][32*32];                  // adjacency [t][n][g] (bf16)
  __shared__ float sh_ge[H_];
  __shared__ float sh_part[4][OUT_];              // Wo-tail partials
  __shared__ float sh_rowsum[N_];

  // ---- zero LDS (rows never written later must be 0) -----------------------
  for (int i=tid;i<(32*XCS)/2;i+=TB){ ((int*)XcH)[i]=0; ((int*)XcL)[i]=0; }
  for (int i=tid;i<(32*XMS)/2;i+=TB){ ((int*)XmH)[i]=0; }
  for (int i=tid;i<(112*ST2)/2;i+=TB){ ((int*)XcT)[i]=0; }
  for (int i=tid;i<(4*32*XMS)/2;i+=TB){ ((int*)XyH)[i]=0; }
  if (tid < H_) sh_ge[tid]=0.0f;
  if (tid < N_) sh_rowsum[tid]=0.0f;
  __syncthreads();

  // ---- edge staging: adjacency planes + row sums (tid == (n,g), TB==N*N) ---
  {
    int n = tid>>5, g = tid&31;
    const float4 ev = *(const float4*)(edges + (((size_t)b*N_+n)*N_+g)*4);
    float adj = ev.x+ev.y+ev.z+ev.w;
    if (adj != 0.0f) atomicAdd(&sh_rowsum[n], adj);
    Aw[0][n*32+g] = f2bf(ev.x);
    Aw[1][n*32+g] = f2bf(ev.y);
    Aw[2][n*32+g] = f2bf(ev.z);
    Aw[3][n*32+g] = f2bf(ev.w);
  }
  for (int p=tid; p<N_*F_; p+=TB){              // grid-stride: 1280 > TB
    int n = p/F_, f = p%F_;
    float x = nodes[((size_t)b*N_+n)*F_ + f];
    short hi,lo; bsplit(x,hi,lo);
    XcH[n*XCS+f]=hi;      XcL[n*XCS+f]=lo;      // h init rows 0..39
    XcH[n*XCS+100+f]=hi;                        // cat-tail rows 100..139
    XcT[f*ST2+n]=hi;                            // transposed h init
  }
  __syncthreads();

  const int jmt = w>>1, nt = w&1;               // task (w<14)
  const bool task = (w < 14);
  const int nrow = nt*16 + (lane&15);           // this lane's B-row (node)
  const int boff = (lane>>4)*8;                 // this lane's k-offset in frag

  for (int pass=0; pass<3; ++pass){
    // ---- Y-agg: Y_t[k-tile jmt][n-tile nt] = XcT · Aw_t, 4 MFMA ------------
    if (task){
      bf16x8 at = *(const bf16x8*)&XcT[(jmt*16+(lane&15))*ST2 + boff];
      int kbase = jmt*16 + boff/2;              // = jmt*16 + quad*4
#pragma unroll
      for (int t=0;t<4;++t){
        bf16x8 bt = *(const bf16x8*)&Aw[t][nrow*32 + boff];
        f32x4 D = (f32x4)0.0f;
        D = MFMA(at, bt, D);
        short4 pk;                               // 4 contiguous k -> one b64
        pk.x = f2bf(D[0]); pk.y = f2bf(D[1]);
        pk.z = f2bf(D[2]); pk.w = f2bf(D[3]);
        *(short4*)&XyH[t][nrow*XMS + kbase] = pk;
      }
    }
    __syncthreads();
    // ---- region 1: msg (4 t-groups of 4 mm1) + hh (B shared) + Xm write ----
    f32x4 Ch0=(f32x4)0.0f, Ch1=(f32x4)0.0f, Ch2=(f32x4)0.0f;
    if (task){
      f32x4 Cm=(f32x4)0.0f;
#pragma unroll 1
      for (int t=0;t<4;++t){
        const short* pa = AFhi + ((size_t)(t*28 + jmt*4))*512 + lane*8;
        const short* pb = XyH[t] + nrow*XMS + boff;
        bf16x8 a0 = *(const bf16x8*)(pa);
        bf16x8 a1 = *(const bf16x8*)(pa+512);
        bf16x8 a2 = *(const bf16x8*)(pa+1024);
        bf16x8 a3 = *(const bf16x8*)(pa+1536);
        bf16x8 b0 = *(const bf16x8*)(pb);
        bf16x8 b1 = *(const bf16x8*)(pb+32);
        bf16x8 b2 = *(const bf16x8*)(pb+64);
        bf16x8 b3 = *(const bf16x8*)(pb+96);
        Cm = MFMA(a0,b0,Cm); Cm = MFMA(a1,b1,Cm);
        Cm = MFMA(a2,b2,Cm); Cm = MFMA(a3,b3,Cm);
      }
      {  // hh gates: load XcH B-frags ONCE, reuse for 3 gates
        const short* pb = XcH + nrow*XCS + boff;
        bf16x8 b0 = *(const bf16x8*)(pb);
        bf16x8 b1 = *(const bf16x8*)(pb+32);
        bf16x8 b2 = *(const bf16x8*)(pb+64);
        bf16x8 b3 = *(const bf16x8*)(pb+96);
        const short* pa = AFhi + ((size_t)(112 + 3*28 + jmt*4))*512 + lane*8;
        {
          bf16x8 a0=*(const bf16x8*)(pa),      a1=*(const bf16x8*)(pa+512);
          bf16x8 a2=*(const bf16x8*)(pa+1024), a3=*(const bf16x8*)(pa+1536);
          Ch0 = MFMA(a0,b0,Ch0); Ch0 = MFMA(a1,b1,Ch0);
          Ch0 = MFMA(a2,b2,Ch0); Ch0 = MFMA(a3,b3,Ch0);
        }
        pa += 28*512;
        {
          bf16x8 a0=*(const bf16x8*)(pa),      a1=*(const bf16x8*)(pa+512);
          bf16x8 a2=*(const bf16x8*)(pa+1024), a3=*(const bf16x8*)(pa+1536);
          Ch1 = MFMA(a0,b0,Ch1); Ch1 = MFMA(a1,b1,Ch1);
          Ch1 = MFMA(a2,b2,Ch1); Ch1 = MFMA(a3,b3,Ch1);
        }
        pa += 28*512;
        {
          bf16x8 a0=*(const bf16x8*)(pa),      a1=*(const bf16x8*)(pa+512);
          bf16x8 a2=*(const bf16x8*)(pa+1024), a3=*(const bf16x8*)(pa+1536);
          Ch2 = MFMA(a0,b0,Ch2); Ch2 = MFMA(a1,b1,Ch2);
          Ch2 = MFMA(a2,b2,Ch2); Ch2 = MFMA(a3,b3,Ch2);
        }
      }
      for (int r=0;r<4;++r){                   // Xm write (disjoint from Xy/Xc)
        int row = jmt*16 + (lane>>4)*4 + r;
        if (row<100) XmH[nrow*XMS+row] = f2bf(Cm[r]);
      }
    }
    __syncthreads();
    // ---- region 2: ih gates (B=Xm shared) + GRU elementwise ----------------
    if (task){
      f32x4 Ci0=(f32x4)0.0f, Ci1=(f32x4)0.0f, Ci2=(f32x4)0.0f;
      {
        const short* pb = XmH + nrow*XMS + boff;
        bf16x8 b0 = *(const bf16x8*)(pb);
        bf16x8 b1 = *(const bf16x8*)(pb+32);
        bf16x8 b2 = *(const bf16x8*)(pb+64);
        bf16x8 b3 = *(const bf16x8*)(pb+96);
        const short* pa = AFhi + ((size_t)(112 + jmt*4))*512 + lane*8;
        {
          bf16x8 a0=*(const bf16x8*)(pa),      a1=*(const bf16x8*)(pa+512);
          bf16x8 a2=*(const bf16x8*)(pa+1024), a3=*(const bf16x8*)(pa+1536);
          Ci0 = MFMA(a0,b0,Ci0); Ci0 = MFMA(a1,b1,Ci0);
          Ci0 = MFMA(a2,b2,Ci0); Ci0 = MFMA(a3,b3,Ci0);
        }
        pa += 28*512;
        {
          bf16x8 a0=*(const bf16x8*)(pa),      a1=*(const bf16x8*)(pa+512);
          bf16x8 a2=*(const bf16x8*)(pa+1024), a3=*(const bf16x8*)(pa+1536);
          Ci1 = MFMA(a0,b0,Ci1); Ci1 = MFMA(a1,b1,Ci1);
          Ci1 = MFMA(a2,b2,Ci1); Ci1 = MFMA(a3,b3,Ci1);
        }
        pa += 28*512;
        {
          bf16x8 a0=*(const bf16x8*)(pa),      a1=*(const bf16x8*)(pa+512);
          bf16x8 a2=*(const bf16x8*)(pa+1024), a3=*(const bf16x8*)(pa+1536);
          Ci2 = MFMA(a0,b0,Ci2); Ci2 = MFMA(a1,b1,Ci2);
          Ci2 = MFMA(a2,b2,Ci2); Ci2 = MFMA(a3,b3,Ci2);
        }
      }
      bool msk = (sh_rowsum[nrow] != 0.0f);
#pragma unroll
      for (int r=0;r<4;++r){
        int row = jmt*16 + (lane>>4)*4 + r;
        if (row<100){
          float ho = bf2f(XcH[nrow*XCS+row]) + bf2f(XcL[nrow*XCS+row]);
          float rr = sigmoidf_(Ci0[r]+Ch0[r] + b_ih[row]     + b_hh[row]);
          float zz = sigmoidf_(Ci1[r]+Ch1[r] + b_ih[100+row] + b_hh[100+row]);
          float nn = tanhf_(Ci2[r] + b_ih[200+row] + rr*(Ch2[r] + b_hh[200+row]));
          float hnew = (1.0f-zz)*nn + zz*ho;
          if (!msk) hnew = ho;
          short hi,lo; bsplit(hnew,hi,lo);
          XcH[nrow*XCS+row]=hi; XcL[nrow*XCS+row]=lo;
          XcT[row*ST2+nrow]=hi;                 // keep transposed copy current
        }
      }
    }
    __syncthreads();
  }

  // ---- readout: gate/emb GEMMs (A hi+lo, B=XcH shared), masked sum ---------
  f32x4 Cg=(f32x4)0.0f, Ce=(f32x4)0.0f;
  if (task){
    const short* pb = XcH + nrow*XCS + boff;
    bf16x8 b0 = *(const bf16x8*)(pb);
    bf16x8 b1 = *(const bf16x8*)(pb+32);
    bf16x8 b2 = *(const bf16x8*)(pb+64);
    bf16x8 b3 = *(const bf16x8*)(pb+96);
    bf16x8 b4 = *(const bf16x8*)(pb+128);
    {  // Wg: blocks 280+jmt*5 .. +4 (hi) and same-idx lo
      const short* ph = AFhi + ((size_t)(280 + jmt*5))*512 + lane*8;
      const short* pl = AFlo + ((size_t)(jmt*5))*512 + lane*8;
      Cg = MFMA(*(const bf16x8*)(ph),      b0, Cg);
      Cg = MFMA(*(const bf16x8*)(pl),      b0, Cg);
      Cg = MFMA(*(const bf16x8*)(ph+512),  b1, Cg);
      Cg = MFMA(*(const bf16x8*)(pl+512),  b1, Cg);
      Cg = MFMA(*(const bf16x8*)(ph+1024), b2, Cg);
      Cg = MFMA(*(const bf16x8*)(pl+1024), b2, Cg);
      Cg = MFMA(*(const bf16x8*)(ph+1536), b3, Cg);
      Cg = MFMA(*(const bf16x8*)(pl+1536), b3, Cg);
      Cg = MFMA(*(const bf16x8*)(ph+2048), b4, Cg);
      Cg = MFMA(*(const bf16x8*)(pl+2048), b4, Cg);
    }
    {  // We: blocks 315+jmt*4 .. +3 (hi), lo at (blk-280)
      const short* ph = AFhi + ((size_t)(315 + jmt*4))*512 + lane*8;
      const short* pl = AFlo + ((size_t)(35 + jmt*4))*512 + lane*8;
      Ce = MFMA(*(const bf16x8*)(ph),      b0, Ce);
      Ce = MFMA(*(const bf16x8*)(pl),      b0, Ce);
      Ce = MFMA(*(const bf16x8*)(ph+512),  b1, Ce);
      Ce = MFMA(*(const bf16x8*)(pl+512),  b1, Ce);
      Ce = MFMA(*(const bf16x8*)(ph+1024), b2, Ce);
      Ce = MFMA(*(const bf16x8*)(pl+1024), b2, Ce);
      Ce = MFMA(*(const bf16x8*)(ph+1536), b3, Ce);
      Ce = MFMA(*(const bf16x8*)(pl+1536), b3, Ce);
    }
    bool msk = (sh_rowsum[nrow] != 0.0f);
#pragma unroll
    for (int r=0;r<4;++r){
      int row = jmt*16 + (lane>>4)*4 + r;
      float v = 0.0f;
      if (row<100){
        float gate = sigmoidf_(Cg[r] + bg[row]);
        float emb  = gate*(Ce[r] + be[row]);
        v = msk ? emb : 0.0f;
      }
      v += __shfl_xor(v, 1);                   // reduce across 16 cols
      v += __shfl_xor(v, 2);
      v += __shfl_xor(v, 4);
      v += __shfl_xor(v, 8);
      if (row<100 && (lane&15)==0) atomicAdd(&sh_ge[row], v);
    }
  }
  __syncthreads();
  // ---- out = graph_emb @ Wo + bo : 512 threads, 4 k-chunks of 25 -----------
  if (tid < 512){
    int o = tid & 127, q = tid >> 7;           // lanes consecutive in o -> coalesced
    float s = 0.0f;
    int k0 = 25*q;
#pragma unroll 5
    for (int k=k0; k<k0+25; ++k) s += sh_ge[k]*Wo[k*OUT_+o];
    sh_part[q][o] = s;
  }
  __syncthreads();
  if (tid < OUT_){
    out[(size_t)b*OUT_ + tid] = bo[tid] + sh_part[0][tid] + sh_part[1][tid]
                              + sh_part[2][tid] + sh_part[3][tid];
  }
}

extern "C" void kernel_launch(void* const* d_in, const int* in_sizes, int n_in,
                              void* d_out, int out_size, void* d_ws, size_t ws_size,
                              hipStream_t stream){
  const float* nodes = (const float*)d_in[0];
  const float* edges = (const float*)d_in[1];
  const float* W_msg = (const float*)d_in[2];
  const float* W_ih  = (const float*)d_in[3];
  const float* W_hh  = (const float*)d_in[4];
  const float* b_ih  = (const float*)d_in[5];
  const float* b_hh  = (const float*)d_in[6];
  const float* Wg    = (const float*)d_in[7];
  const float* bg    = (const float*)d_in[8];
  const float* We    = (const float*)d_in[9];
  const float* be    = (const float*)d_in[10];
  const float* Wo    = (const float*)d_in[11];
  const float* bo    = (const float*)d_in[12];

  short* AFhi = (short*)d_ws;                        // 343*512 shorts = 343 KB
  short* AFlo = AFhi + (size_t)NBLK*512;             //  63*512 shorts =  63 KB

  prep_frags4<<<(NBLK*512 + 255)/256, 256, 0, stream>>>(W_msg, W_ih, W_hh, Wg, We,
                                                        AFhi, AFlo);
  mpnn_mfma<<<B_, TB, 0, stream>>>(nodes, edges, AFhi, AFlo, b_ih, b_hh, bg, be,
                                   Wo, bo, (float*)d_out);
}

// Round 17
// 113.007 us; speedup vs baseline: 1.3622x; 1.0133x over previous
//
#include <hip/hip_runtime.h>
#include <cstddef>
#include <cstdint>

// B=256, N=32, F=40, H=M=100, EF=4, OUT=128, 3 passes.
#define B_   256
#define N_   32
#define F_   40
#define H_   100
#define OUT_ 128
#define TB   1024         // 16 waves/block -> 4 waves/SIMD, 1 block/CU
#define XCS  168          // XcH row stride (shorts), 16B-multiple
#define XMS  136          // Xm / Xy row stride (shorts), 16B-multiple
#define ST2  40           // XcT row stride (shorts): [k][g], 16B-multiple
#define NBLK 343          // AFhi blocks: 112 msg + 168 GRU + 35 Wg + 28 We
#define NLO  63           // AFlo blocks (readout lo)

using bf16x8 = __attribute__((ext_vector_type(8))) short;   // 8 bf16 (4 VGPRs)
using f32x4  = __attribute__((ext_vector_type(4))) float;   // MFMA C/D

#define MFMA(a,b,c) __builtin_amdgcn_mfma_f32_16x16x32_bf16((a),(b),(c),0,0,0)

__device__ __forceinline__ float sigmoidf_(float x){ return 1.0f/(1.0f+__expf(-x)); }
__device__ __forceinline__ float tanhf_(float x){           // fast tanh via __expf
  float e = __expf(2.0f*x);
  return 1.0f - 2.0f/(e+1.0f);
}
__device__ __forceinline__ float bf2f(short s){ return __uint_as_float(((uint32_t)(uint16_t)s)<<16); }
__device__ __forceinline__ short f2bf(float x){             // round-to-nearest-even
  uint32_t u = __float_as_uint(x);
  return (short)((u + 0x7FFFu + ((u>>16)&1u))>>16);
}
__device__ __forceinline__ void bsplit(float x, short& hi, short& lo){
  hi = f2bf(x);
  lo = f2bf(x - bf2f(hi));
}

// ---------------------------------------------------------------------------
// Weight pre-pack v4 (unchanged layout): SLOT-indexed, OOR slots get 0.
//   [0,112)   W_msg : t*28 + jmt*4 + ks        A[m][h]=W_msg[m, h, t]
//   [112,280) GRU   : 112+mat*28+jmt*4+ks      mat: ihr,ihz,ihn,hhr,hhz,hhn
//   [280,315) Wg^T  : 280+jmt*5+ks (K=140)     A[j][k]=Wg[k, j]  (hi+lo)
//   [315,343) We^T  : 315+jmt*4+ks             A[j][k]=We[k, j]  (hi+lo)
// ---------------------------------------------------------------------------
__global__ void prep_frags4(const float* __restrict__ Wmsg,
                            const float* __restrict__ Wih,
                            const float* __restrict__ Whh,
                            const float* __restrict__ Wg,
                            const float* __restrict__ We,
                            short* __restrict__ AFhi,
                            short* __restrict__ AFlo){
  int slot = blockIdx.x*blockDim.x + threadIdx.x;
  if (slot >= NBLK*512) return;
  int blk = slot>>9, r = slot&511, lane = r>>3, jj = r&7;
  int m = lane&15, q = lane>>4, kl = q*8+jj;
  float v = 0.0f;
  if (blk < 112){
    int t = blk/28, rem = blk%28, jmt = rem>>2, ks = rem&3;
    int mg = jmt*16+m, h = ks*32+kl;
    if (mg<100 && h<100) v = Wmsg[(mg*100+h)*4 + t];
    AFhi[slot] = f2bf(v);
  } else if (blk < 280){
    int bb = blk-112, mat = bb/28, rem = bb%28, jmt = rem>>2, ks = rem&3;
    int mg = jmt*16+m, k = ks*32+kl;
    if (mg<100 && k<100)
      v = (mat<3) ? Wih[(mat*100+mg)*100+k] : Whh[((mat-3)*100+mg)*100+k];
    AFhi[slot] = f2bf(v);
  } else if (blk < 315){
    int bb = blk-280, jmt = bb/5, ks = bb%5;
    int mg = jmt*16+m, k = ks*32+kl;
    if (mg<100 && k<140) v = Wg[k*100+mg];
    short hi,lo; bsplit(v,hi,lo);
    AFhi[slot] = hi;
    AFlo[(size_t)(blk-280)*512 + r] = lo;
  } else {
    int bb = blk-315, jmt = bb>>2, ks = bb&3;
    int mg = jmt*16+m, k = ks*32+kl;
    if (mg<100 && k<100) v = We[k*100+mg];
    short hi,lo; bsplit(v,hi,lo);
    AFhi[slot] = hi;
    AFlo[(size_t)(blk-280)*512 + r] = lo;
  }
}

// ---------------------------------------------------------------------------
// Fused MPNN. 14 tile-tasks (jmt<7 x nt<2), one per wave. 3 barriers/pass:
//  [Y-agg (4 MFMA, short4 C-writes) + hh gates (12 mm1, B shared)] bar
//  [msg (16 mm1) + Xm short4 write] bar
//  [ih (12 mm1, B shared) + GRU elementwise (h-state in REGISTERS)] bar
// h-state: task map is pass-invariant, so each lane owns its 4 GRU cells in
// fp32 registers across passes -> no XcL buffer, no ho LDS reads, exact state.
// Quad rows are contiguous and 100%4==0 -> row-writes are single short4 b64s.
// GEMM loops: immediate-offset unroll-4, outer #pragma unroll 1 (spill guard).
// ---------------------------------------------------------------------------
__global__ __launch_bounds__(TB, 4) void mpnn_mfma(
    const float* __restrict__ nodes, const float* __restrict__ edges,
    const short* __restrict__ AFhi, const short* __restrict__ AFlo,
    const float* __restrict__ b_ih, const float* __restrict__ b_hh,
    const float* __restrict__ bg, const float* __restrict__ be,
    const float* __restrict__ Wo, const float* __restrict__ bo,
    float* __restrict__ out){
  const int b = blockIdx.x;
  const int tid = threadIdx.x;
  const int lane = tid & 63;
  const int w = tid >> 6;

  __shared__ short XcH[32*XCS];                   // cat: h | nodes(100..139) | 0
  __shared__ short XcT[112*ST2];                  // transposed h [k][g]
  __shared__ short XmH[32*XMS];                   // messages (bf16)
  __shared__ short XyH[4][32*XMS];                // per-type Y_t (bf16) [n][k]
  __shared__ short Aw[4][32*32];                  // adjacency [t][n][g] (bf16)
  __shared__ float sh_ge[H_];
  __shared__ float sh_part[4][OUT_];              // Wo-tail partials
  __shared__ float sh_rowsum[N_];

  // ---- zero LDS (rows never written later must be 0) -----------------------
  for (int i=tid;i<(32*XCS)/2;i+=TB){ ((int*)XcH)[i]=0; }
  for (int i=tid;i<(32*XMS)/2;i+=TB){ ((int*)XmH)[i]=0; }
  for (int i=tid;i<(112*ST2)/2;i+=TB){ ((int*)XcT)[i]=0; }
  for (int i=tid;i<(4*32*XMS)/2;i+=TB){ ((int*)XyH)[i]=0; }
  if (tid < H_) sh_ge[tid]=0.0f;
  if (tid < N_) sh_rowsum[tid]=0.0f;
  __syncthreads();

  // ---- edge staging: adjacency planes + row sums (tid == (n,g), TB==N*N) ---
  {
    int n = tid>>5, g = tid&31;
    const float4 ev = *(const float4*)(edges + (((size_t)b*N_+n)*N_+g)*4);
    float adj = ev.x+ev.y+ev.z+ev.w;
    if (adj != 0.0f) atomicAdd(&sh_rowsum[n], adj);
    Aw[0][n*32+g] = f2bf(ev.x);
    Aw[1][n*32+g] = f2bf(ev.y);
    Aw[2][n*32+g] = f2bf(ev.z);
    Aw[3][n*32+g] = f2bf(ev.w);
  }
  for (int p=tid; p<N_*F_; p+=TB){              // grid-stride: 1280 > TB
    int n = p/F_, f = p%F_;
    float x = nodes[((size_t)b*N_+n)*F_ + f];
    short hi = f2bf(x);
    XcH[n*XCS+f]=hi;                            // h init rows 0..39
    XcH[n*XCS+100+f]=hi;                        // cat-tail rows 100..139
    XcT[f*ST2+n]=hi;                            // transposed h init
  }

  const int jmt = w>>1, nt = w&1;               // task (w<14)
  const bool task = (w < 14);
  const int nrow = nt*16 + (lane&15);           // this lane's B-row (node)
  const int boff = (lane>>4)*8;                 // this lane's k-offset in frag
  const int rowbase = jmt*16 + (lane>>4)*4;     // this lane's 4 output rows

  // ---- per-lane fp32 GRU state (pass-invariant cell ownership) -------------
  float hst[4] = {0.f,0.f,0.f,0.f};
  if (task){
#pragma unroll
    for (int r=0;r<4;++r){
      int row = rowbase + r;
      if (row < F_) hst[r] = nodes[((size_t)b*N_+nrow)*F_ + row];
    }
  }
  __syncthreads();

  for (int pass=0; pass<3; ++pass){
    // ---- region 0: Y-agg (4 MFMA, short4 writes) + hh gates (B shared) -----
    f32x4 Ch0=(f32x4)0.0f, Ch1=(f32x4)0.0f, Ch2=(f32x4)0.0f;
    if (task){
      {
        bf16x8 at = *(const bf16x8*)&XcT[(jmt*16+(lane&15))*ST2 + boff];
        int kbase = jmt*16 + (boff>>1);         // = jmt*16 + quad*4
#pragma unroll
        for (int t=0;t<4;++t){
          bf16x8 bt = *(const bf16x8*)&Aw[t][nrow*32 + boff];
          f32x4 D = (f32x4)0.0f;
          D = MFMA(at, bt, D);
          short4 pk;                             // 4 contiguous k -> one b64
          pk.x = f2bf(D[0]); pk.y = f2bf(D[1]);
          pk.z = f2bf(D[2]); pk.w = f2bf(D[3]);
          *(short4*)&XyH[t][nrow*XMS + kbase] = pk;
        }
      }
      {  // hh gates: load XcH B-frags ONCE, reuse for 3 gates
        const short* pb = XcH + nrow*XCS + boff;
        bf16x8 b0 = *(const bf16x8*)(pb);
        bf16x8 b1 = *(const bf16x8*)(pb+32);
        bf16x8 b2 = *(const bf16x8*)(pb+64);
        bf16x8 b3 = *(const bf16x8*)(pb+96);
        const short* pa = AFhi + ((size_t)(112 + 3*28 + jmt*4))*512 + lane*8;
        {
          bf16x8 a0=*(const bf16x8*)(pa),      a1=*(const bf16x8*)(pa+512);
          bf16x8 a2=*(const bf16x8*)(pa+1024), a3=*(const bf16x8*)(pa+1536);
          Ch0 = MFMA(a0,b0,Ch0); Ch0 = MFMA(a1,b1,Ch0);
          Ch0 = MFMA(a2,b2,Ch0); Ch0 = MFMA(a3,b3,Ch0);
        }
        pa += 28*512;
        {
          bf16x8 a0=*(const bf16x8*)(pa),      a1=*(const bf16x8*)(pa+512);
          bf16x8 a2=*(const bf16x8*)(pa+1024), a3=*(const bf16x8*)(pa+1536);
          Ch1 = MFMA(a0,b0,Ch1); Ch1 = MFMA(a1,b1,Ch1);
          Ch1 = MFMA(a2,b2,Ch1); Ch1 = MFMA(a3,b3,Ch1);
        }
        pa += 28*512;
        {
          bf16x8 a0=*(const bf16x8*)(pa),      a1=*(const bf16x8*)(pa+512);
          bf16x8 a2=*(const bf16x8*)(pa+1024), a3=*(const bf16x8*)(pa+1536);
          Ch2 = MFMA(a0,b0,Ch2); Ch2 = MFMA(a1,b1,Ch2);
          Ch2 = MFMA(a2,b2,Ch2); Ch2 = MFMA(a3,b3,Ch2);
        }
      }
    }
    __syncthreads();
    // ---- region 1: msg (4 t-groups of 4 mm1) + Xm short4 write -------------
    if (task){
      f32x4 Cm=(f32x4)0.0f;
#pragma unroll 1
      for (int t=0;t<4;++t){
        const short* pa = AFhi + ((size_t)(t*28 + jmt*4))*512 + lane*8;
        const short* pb = XyH[t] + nrow*XMS + boff;
        bf16x8 a0 = *(const bf16x8*)(pa);
        bf16x8 a1 = *(const bf16x8*)(pa+512);
        bf16x8 a2 = *(const bf16x8*)(pa+1024);
        bf16x8 a3 = *(const bf16x8*)(pa+1536);
        bf16x8 b0 = *(const bf16x8*)(pb);
        bf16x8 b1 = *(const bf16x8*)(pb+32);
        bf16x8 b2 = *(const bf16x8*)(pb+64);
        bf16x8 b3 = *(const bf16x8*)(pb+96);
        Cm = MFMA(a0,b0,Cm); Cm = MFMA(a1,b1,Cm);
        Cm = MFMA(a2,b2,Cm); Cm = MFMA(a3,b3,Cm);
      }
      if (rowbase < 100){                        // quads never straddle 100
        short4 pk;
        pk.x = f2bf(Cm[0]); pk.y = f2bf(Cm[1]);
        pk.z = f2bf(Cm[2]); pk.w = f2bf(Cm[3]);
        *(short4*)&XmH[nrow*XMS + rowbase] = pk;
      }
    }
    __syncthreads();
    // ---- region 2: ih gates (B=Xm shared) + GRU elementwise (reg state) ----
    if (task){
      f32x4 Ci0=(f32x4)0.0f, Ci1=(f32x4)0.0f, Ci2=(f32x4)0.0f;
      {
        const short* pb = XmH + nrow*XMS + boff;
        bf16x8 b0 = *(const bf16x8*)(pb);
        bf16x8 b1 = *(const bf16x8*)(pb+32);
        bf16x8 b2 = *(const bf16x8*)(pb+64);
        bf16x8 b3 = *(const bf16x8*)(pb+96);
        const short* pa = AFhi + ((size_t)(112 + jmt*4))*512 + lane*8;
        {
          bf16x8 a0=*(const bf16x8*)(pa),      a1=*(const bf16x8*)(pa+512);
          bf16x8 a2=*(const bf16x8*)(pa+1024), a3=*(const bf16x8*)(pa+1536);
          Ci0 = MFMA(a0,b0,Ci0); Ci0 = MFMA(a1,b1,Ci0);
          Ci0 = MFMA(a2,b2,Ci0); Ci0 = MFMA(a3,b3,Ci0);
        }
        pa += 28*512;
        {
          bf16x8 a0=*(const bf16x8*)(pa),      a1=*(const bf16x8*)(pa+512);
          bf16x8 a2=*(const bf16x8*)(pa+1024), a3=*(const bf16x8*)(pa+1536);
          Ci1 = MFMA(a0,b0,Ci1); Ci1 = MFMA(a1,b1,Ci1);
          Ci1 = MFMA(a2,b2,Ci1); Ci1 = MFMA(a3,b3,Ci1);
        }
        pa += 28*512;
        {
          bf16x8 a0=*(const bf16x8*)(pa),      a1=*(const bf16x8*)(pa+512);
          bf16x8 a2=*(const bf16x8*)(pa+1024), a3=*(const bf16x8*)(pa+1536);
          Ci2 = MFMA(a0,b0,Ci2); Ci2 = MFMA(a1,b1,Ci2);
          Ci2 = MFMA(a2,b2,Ci2); Ci2 = MFMA(a3,b3,Ci2);
        }
      }
      if (rowbase < 100){
        bool msk = (sh_rowsum[nrow] != 0.0f);
        short4 pk;
#pragma unroll
        for (int r=0;r<4;++r){
          int row = rowbase + r;
          float ho = hst[r];
          float rr = sigmoidf_(Ci0[r]+Ch0[r] + b_ih[row]     + b_hh[row]);
          float zz = sigmoidf_(Ci1[r]+Ch1[r] + b_ih[100+row] + b_hh[100+row]);
          float nn = tanhf_(Ci2[r] + b_ih[200+row] + rr*(Ch2[r] + b_hh[200+row]));
          float hnew = (1.0f-zz)*nn + zz*ho;
          if (!msk) hnew = ho;
          hst[r] = hnew;
          short hb = f2bf(hnew);
          ((short*)&pk)[r] = hb;
          XcT[row*ST2+nrow] = hb;               // transposed copy (scatter)
        }
        *(short4*)&XcH[nrow*XCS + rowbase] = pk;
      }
    }
    __syncthreads();
  }

  // ---- readout: gate/emb GEMMs (A hi+lo, B=XcH shared), masked sum ---------
  f32x4 Cg=(f32x4)0.0f, Ce=(f32x4)0.0f;
  if (task){
    const short* pb = XcH + nrow*XCS + boff;
    bf16x8 b0 = *(const bf16x8*)(pb);
    bf16x8 b1 = *(const bf16x8*)(pb+32);
    bf16x8 b2 = *(const bf16x8*)(pb+64);
    bf16x8 b3 = *(const bf16x8*)(pb+96);
    bf16x8 b4 = *(const bf16x8*)(pb+128);
    {  // Wg: blocks 280+jmt*5 .. +4 (hi) and same-idx lo
      const short* ph = AFhi + ((size_t)(280 + jmt*5))*512 + lane*8;
      const short* pl = AFlo + ((size_t)(jmt*5))*512 + lane*8;
      Cg = MFMA(*(const bf16x8*)(ph),      b0, Cg);
      Cg = MFMA(*(const bf16x8*)(pl),      b0, Cg);
      Cg = MFMA(*(const bf16x8*)(ph+512),  b1, Cg);
      Cg = MFMA(*(const bf16x8*)(pl+512),  b1, Cg);
      Cg = MFMA(*(const bf16x8*)(ph+1024), b2, Cg);
      Cg = MFMA(*(const bf16x8*)(pl+1024), b2, Cg);
      Cg = MFMA(*(const bf16x8*)(ph+1536), b3, Cg);
      Cg = MFMA(*(const bf16x8*)(pl+1536), b3, Cg);
      Cg = MFMA(*(const bf16x8*)(ph+2048), b4, Cg);
      Cg = MFMA(*(const bf16x8*)(pl+2048), b4, Cg);
    }
    {  // We: blocks 315+jmt*4 .. +3 (hi), lo at (blk-280)
      const short* ph = AFhi + ((size_t)(315 + jmt*4))*512 + lane*8;
      const short* pl = AFlo + ((size_t)(35 + jmt*4))*512 + lane*8;
      Ce = MFMA(*(const bf16x8*)(ph),      b0, Ce);
      Ce = MFMA(*(const bf16x8*)(pl),      b0, Ce);
      Ce = MFMA(*(const bf16x8*)(ph+512),  b1, Ce);
      Ce = MFMA(*(const bf16x8*)(pl+512),  b1, Ce);
      Ce = MFMA(*(const bf16x8*)(ph+1024), b2, Ce);
      Ce = MFMA(*(const bf16x8*)(pl+1024), b2, Ce);
      Ce = MFMA(*(const bf16x8*)(ph+1536), b3, Ce);
      Ce = MFMA(*(const bf16x8*)(pl+1536), b3, Ce);
    }
    bool msk = (sh_rowsum[nrow] != 0.0f);
#pragma unroll
    for (int r=0;r<4;++r){
      int row = rowbase + r;
      float v = 0.0f;
      if (row<100){
        float gate = sigmoidf_(Cg[r] + bg[row]);
        float emb  = gate*(Ce[r] + be[row]);
        v = msk ? emb : 0.0f;
      }
      v += __shfl_xor(v, 1);                   // reduce across 16 cols
      v += __shfl_xor(v, 2);
      v += __shfl_xor(v, 4);
      v += __shfl_xor(v, 8);
      if (row<100 && (lane&15)==0) atomicAdd(&sh_ge[row], v);
    }
  }
  __syncthreads();
  // ---- out = graph_emb @ Wo + bo : 512 threads, 4 k-chunks of 25 -----------
  if (tid < 512){
    int o = tid & 127, q = tid >> 7;           // lanes consecutive in o -> coalesced
    float s = 0.0f;
    int k0 = 25*q;
#pragma unroll 5
    for (int k=k0; k<k0+25; ++k) s += sh_ge[k]*Wo[k*OUT_+o];
    sh_part[q][o] = s;
  }
  __syncthreads();
  if (tid < OUT_){
    out[(size_t)b*OUT_ + tid] = bo[tid] + sh_part[0][tid] + sh_part[1][tid]
                              + sh_part[2][tid] + sh_part[3][tid];
  }
}

extern "C" void kernel_launch(void* const* d_in, const int* in_sizes, int n_in,
                              void* d_out, int out_size, void* d_ws, size_t ws_size,
                              hipStream_t stream){
  const float* nodes = (const float*)d_in[0];
  const float* edges = (const float*)d_in[1];
  const float* W_msg = (const float*)d_in[2];
  const float* W_ih  = (const float*)d_in[3];
  const float* W_hh  = (const float*)d_in[4];
  const float* b_ih  = (const float*)d_in[5];
  const float* b_hh  = (const float*)d_in[6];
  const float* Wg    = (const float*)d_in[7];
  const float* bg    = (const float*)d_in[8];
  const float* We    = (const float*)d_in[9];
  const float* be    = (const float*)d_in[10];
  const float* Wo    = (const float*)d_in[11];
  const float* bo    = (const float*)d_in[12];

  short* AFhi = (short*)d_ws;                        // 343*512 shorts = 343 KB
  short* AFlo = AFhi + (size_t)NBLK*512;             //  63*512 shorts =  63 KB

  prep_frags4<<<(NBLK*512 + 255)/256, 256, 0, stream>>>(W_msg, W_ih, W_hh, Wg, We,
                                                        AFhi, AFlo);
  mpnn_mfma<<<B_, TB, 0, stream>>>(nodes, edges, AFhi, AFlo, b_ih, b_hh, bg, be,
                                   Wo, bo, (float*)d_out);
}